// Round 2
// baseline (806.772 us; speedup 1.0000x reference)
//
#include <hip/hip_runtime.h>

// LocalizeAttention: out[bh, n, f, c] = x[bh, n + delta(f), c] (zero at the
// padded volume boundary). H=W=D=24, N=13824, d=32, fn=27, bh=16.
// Write-BW bound (764 MB out). This version amortizes the expensive index
// decomposition over 24 ii-planes per thread: stepping ii advances the
// flattened position by exactly W*D=576, so the loop body is ~7 VALU ops
// per 16 B of traffic (vs ~50 in the 1-thread-per-float4 version).

typedef float v4f __attribute__((ext_vector_type(4)));

constexpr int H = 24, W = 24, D = 24;
constexpr int N = H * W * D;       // 13824
constexpr int FN = 27;
constexpr int COLS = W * D;        // 576
constexpr int INNER = FN * 8;      // 216 float4s per (bh,n) row-group
constexpr int IN_STEP = COLS * 8;          // float4s per ii step (input)
constexpr int OUT_STEP = COLS * INNER;     // float4s per ii step (output)

__global__ __launch_bounds__(256) void localize_kernel(
    const v4f* __restrict__ x4, v4f* __restrict__ out4) {
  int tid = blockIdx.x * 256 + threadIdx.x;   // grid sized exactly

  int inner = tid % INNER;        // f*8 + c4
  int t     = tid / INNER;        // bh*576 + col
  int col   = t % COLS;           // jj*24 + kk
  int bh    = t / COLS;
  int f  = inner >> 3;
  int c4 = inner & 7;
  int jj = col / D;
  int kk = col % D;
  int di = f / 9 - 1;
  int dj = (f / 3) % 3 - 1;
  int dk = f % 3 - 1;

  bool vjk = ((unsigned)(jj + dj) < (unsigned)W) &
             ((unsigned)(kk + dk) < (unsigned)D);
  int lo = di < 0 ? 1 : 0;        // valid ii range: si = ii+di in [0,24)
  int hi = di > 0 ? H - 1 : H;

  int delta  = di * COLS + dj * D + dk;
  int base_n = bh * N + col;                       // t2 at ii=0
  const v4f* in_p = x4 + ((base_n + delta) * 8 + c4);
  v4f* out_p = out4 + (base_n * INNER + inner);

#pragma unroll
  for (int ii = 0; ii < H; ++ii) {
    v4f v = (v4f)(0.0f);
    if (vjk && ii >= lo && ii < hi) v = in_p[ii * IN_STEP];
    __builtin_nontemporal_store(v, out_p + ii * OUT_STEP);
  }
}

extern "C" void kernel_launch(void* const* d_in, const int* in_sizes, int n_in,
                              void* d_out, int out_size, void* d_ws, size_t ws_size,
                              hipStream_t stream) {
  const v4f* x4 = (const v4f*)d_in[0];
  v4f* out4 = (v4f*)d_out;
  // threads = bh(16) * cols(576) * inner(216) = 1,990,656 = 7776 * 256 exactly
  int blocks = 16 * COLS * INNER / 256;
  localize_kernel<<<blocks, 256, 0, stream>>>(x4, out4);
}